// Round 6
// baseline (2646.091 us; speedup 1.0000x reference)
//
#include <hip/hip_runtime.h>
#include <math.h>

// Problem constants
#define T_DIM 8192
#define B_DIM 8
#define D_DIM 256
#define CD_DIM 256
#define HC 512        // HEADS*DIM_HEAD
#define NHEAD 8
#define CHEAD 64
#define NGROUP 32
#define GN_EPS 1e-5f
#define QSCALE 0.125f

// ---------------------------------------------------------------------------
// Workspace layout (bytes) — total ~7.04 MB (was 408 MB; OOB abort suspect)
//   0        chunkstats [b][512][64][2] f32   2,097,152
//   2097152  kstats     [b][512][2]           32,768
//   2129920  ctx        [b][8][64][64]        1,048,576   (zeroed)
//   3178496  gnsum      [b][32]               1,024       (zeroed)
//   3179520  gnsumsq    [b][32]               1,024       (zeroed)
//   3180544  gnmean     [b][32]               1,024
//   3181568  gnrs       [b][32]               1,024
//   3182592  Mm         [b][256][512]         4,194,304
// ---------------------------------------------------------------------------
#define CHUNK_OFF   0ull
#define KST_OFF     2097152ull
#define CTX_OFF     2129920ull
#define GNS_OFF     3178496ull
#define GNQ_OFF     3179520ull
#define GNM_OFF     3180544ull
#define GNR_OFF     3181568ull
#define MM_OFF      3182592ull
#define ZERO_FLOATS 262656   // ctx + gnsum + gnsumsq

__global__ __launch_bounds__(256) void k_zero(float* __restrict__ p, int n) {
  int i = blockIdx.x * 256 + threadIdx.x;
  if (i < n) p[i] = 0.f;
}

// ---------------------------------------------------------------------------
// KA: k = Wkv[0:512] @ cs, per (row, 128-col chunk) max & sumexp -> chunkstats.
// grid (64 chunks, 4 rowblocks of 128, 8 b), 256 thr (16x16), acc 8x8.
// K-order: k0 ascending, kk ascending, fmaf — MUST match KC bitwise.
// ---------------------------------------------------------------------------
__global__ __launch_bounds__(256) void k_kchunk(const float* __restrict__ Wkv,
                                                const float* __restrict__ cs,
                                                float* __restrict__ chunkstats) {
  __shared__ float As[32][132];
  __shared__ float Bs[32][132];
  __shared__ float Rm[128][17];
  __shared__ float Rs[128][17];
  __shared__ float Ms[128];

  const int tid = threadIdx.x;
  const int tx = tid & 15, ty = tid >> 4;
  const int chunk = blockIdx.x;
  const int t0 = chunk * 128;
  const int rb = blockIdx.y * 128;
  const int b = blockIdx.z;

  float acc[8][8];
#pragma unroll
  for (int i = 0; i < 8; ++i)
#pragma unroll
    for (int j = 0; j < 8; ++j) acc[i][j] = 0.f;

  for (int k0 = 0; k0 < CD_DIM; k0 += 32) {
    for (int idx = tid; idx < 128 * 32; idx += 256) {
      int r = idx >> 5, kk = idx & 31;
      As[kk][r] = Wkv[(rb + r) * CD_DIM + k0 + kk];
    }
    for (int idx = tid; idx < 32 * 128; idx += 256) {
      int kk = idx >> 7, c = idx & 127;
      Bs[kk][c] = cs[(b * CD_DIM + k0 + kk) * T_DIM + t0 + c];
    }
    __syncthreads();
#pragma unroll
    for (int kk = 0; kk < 32; ++kk) {
      const float4 a0 = *reinterpret_cast<const float4*>(&As[kk][ty * 8]);
      const float4 a1 = *reinterpret_cast<const float4*>(&As[kk][ty * 8 + 4]);
      const float4 b0 = *reinterpret_cast<const float4*>(&Bs[kk][tx * 8]);
      const float4 b1 = *reinterpret_cast<const float4*>(&Bs[kk][tx * 8 + 4]);
      const float av[8] = {a0.x, a0.y, a0.z, a0.w, a1.x, a1.y, a1.z, a1.w};
      const float bv[8] = {b0.x, b0.y, b0.z, b0.w, b1.x, b1.y, b1.z, b1.w};
#pragma unroll
      for (int i = 0; i < 8; ++i)
#pragma unroll
        for (int j = 0; j < 8; ++j) acc[i][j] = fmaf(av[i], bv[j], acc[i][j]);
    }
    __syncthreads();
  }

  // per-row (128) max over this 128-col chunk
#pragma unroll
  for (int i = 0; i < 8; ++i) {
    float pm = acc[i][0];
#pragma unroll
    for (int j = 1; j < 8; ++j) pm = fmaxf(pm, acc[i][j]);
    Rm[ty * 8 + i][tx] = pm;
  }
  __syncthreads();
  if (tid < 128) {
    float m = Rm[tid][0];
#pragma unroll
    for (int jj = 1; jj < 16; ++jj) m = fmaxf(m, Rm[tid][jj]);
    Ms[tid] = m;
  }
  __syncthreads();
#pragma unroll
  for (int i = 0; i < 8; ++i) {
    const float m = Ms[ty * 8 + i];
    float ps = 0.f;
#pragma unroll
    for (int j = 0; j < 8; ++j) ps += __expf(acc[i][j] - m);
    Rs[ty * 8 + i][tx] = ps;
  }
  __syncthreads();
  if (tid < 128) {
    float s = 0.f;
#pragma unroll
    for (int jj = 0; jj < 16; ++jj) s += Rs[tid][jj];
    const size_t o = ((size_t)(b * HC + rb + tid) * 64 + chunk) * 2;
    chunkstats[o] = Ms[tid];
    chunkstats[o + 1] = s;
  }
}

// ---------------------------------------------------------------------------
// KB: combine 64 chunk stats per row -> (m, 1/Z). grid (512, 8), 64 threads.
// ---------------------------------------------------------------------------
__global__ __launch_bounds__(64) void k_kcomb(const float* __restrict__ chunkstats,
                                              float* __restrict__ kstats) {
  const int r = blockIdx.x;
  const int b = blockIdx.y;
  const int lane = threadIdx.x;
  const size_t o = ((size_t)(b * HC + r) * 64 + lane) * 2;
  float m = chunkstats[o];
  float s = chunkstats[o + 1];
#pragma unroll
  for (int off = 32; off > 0; off >>= 1) {
    float m2 = __shfl_xor(m, off);
    float s2 = __shfl_xor(s, off);
    float mn = fmaxf(m, m2);
    s = s * __expf(m - mn) + s2 * __expf(m2 - mn);
    m = mn;
  }
  if (lane == 0) {
    kstats[(b * HC + r) * 2] = m;
    kstats[(b * HC + r) * 2 + 1] = 1.f / s;
  }
}

// ---------------------------------------------------------------------------
// KC: recompute k (bitwise same order as KA) and v per 64x64 subtile;
// ctx[d][e] += sum_t exp(k[d,t]-m[d])/Z[d] * v[e,t]. grid (8 tc, 8 h, 8 b).
// ---------------------------------------------------------------------------
__global__ __launch_bounds__(256) void k_ctx2(const float* __restrict__ Wkv,
                                              const float* __restrict__ cs,
                                              const float* __restrict__ kstats,
                                              float* __restrict__ ctx) {
  __shared__ float Wk[32][68];
  __shared__ float Wv[32][68];
  __shared__ float Cs[32][68];
  __shared__ float Ks[64][68];  // [tt][d]
  __shared__ float Vs[64][68];  // [tt][e]

  const int tid = threadIdx.x;
  const int tx = tid & 15, ty = tid >> 4;
  const int tc0 = blockIdx.x * 1024;
  const int h = blockIdx.y;
  const int b = blockIdx.z;

  // per-thread k-row stats (d = ty*4+i, fixed for all subtiles)
  float msr[4], zsr[4];
#pragma unroll
  for (int i = 0; i < 4; ++i) {
    msr[i] = kstats[(b * HC + h * CHEAD + ty * 4 + i) * 2];
    zsr[i] = kstats[(b * HC + h * CHEAD + ty * 4 + i) * 2 + 1];
  }

  float cacc[4][4];
#pragma unroll
  for (int i = 0; i < 4; ++i)
#pragma unroll
    for (int j = 0; j < 4; ++j) cacc[i][j] = 0.f;

  for (int sc = 0; sc < 16; ++sc) {
    const int t0 = tc0 + sc * 64;
    float ka[4][4], va[4][4];
#pragma unroll
    for (int i = 0; i < 4; ++i)
#pragma unroll
      for (int j = 0; j < 4; ++j) { ka[i][j] = 0.f; va[i][j] = 0.f; }

    for (int k0 = 0; k0 < CD_DIM; k0 += 32) {
      __syncthreads();  // guard prev reads (Ks/Vs accum of prev sc, prev tiles)
      for (int idx = tid; idx < 32 * 64; idx += 256) {
        int kk = idx >> 6, r = idx & 63;
        Wk[kk][r] = Wkv[(h * CHEAD + r) * CD_DIM + k0 + kk];
        Wv[kk][r] = Wkv[(HC + h * CHEAD + r) * CD_DIM + k0 + kk];
        Cs[kk][r] = cs[(b * CD_DIM + k0 + kk) * T_DIM + t0 + r];
      }
      __syncthreads();
#pragma unroll
      for (int kk = 0; kk < 32; ++kk) {
        const float4 a4 = *reinterpret_cast<const float4*>(&Wk[kk][ty * 4]);
        const float4 w4 = *reinterpret_cast<const float4*>(&Wv[kk][ty * 4]);
        const float4 c4 = *reinterpret_cast<const float4*>(&Cs[kk][tx * 4]);
        const float av[4] = {a4.x, a4.y, a4.z, a4.w};
        const float wv[4] = {w4.x, w4.y, w4.z, w4.w};
        const float cv[4] = {c4.x, c4.y, c4.z, c4.w};
#pragma unroll
        for (int i = 0; i < 4; ++i)
#pragma unroll
          for (int j = 0; j < 4; ++j) {
            ka[i][j] = fmaf(av[i], cv[j], ka[i][j]);
            va[i][j] = fmaf(wv[i], cv[j], va[i][j]);
          }
      }
    }
    __syncthreads();
    // write weighted k and raw v to LDS, transposed to [tt][*]
#pragma unroll
    for (int i = 0; i < 4; ++i)
#pragma unroll
      for (int j = 0; j < 4; ++j) {
        Ks[tx * 4 + j][ty * 4 + i] = __expf(ka[i][j] - msr[i]) * zsr[i];
        Vs[tx * 4 + j][ty * 4 + i] = va[i][j];
      }
    __syncthreads();
    // ctx accumulation
#pragma unroll 8
    for (int tt = 0; tt < 64; ++tt) {
      const float4 kd = *reinterpret_cast<const float4*>(&Ks[tt][ty * 4]);
      const float4 ve = *reinterpret_cast<const float4*>(&Vs[tt][tx * 4]);
      const float kv_[4] = {kd.x, kd.y, kd.z, kd.w};
      const float vv[4] = {ve.x, ve.y, ve.z, ve.w};
#pragma unroll
      for (int i = 0; i < 4; ++i)
#pragma unroll
        for (int j = 0; j < 4; ++j) cacc[i][j] = fmaf(kv_[i], vv[j], cacc[i][j]);
    }
  }
#pragma unroll
  for (int i = 0; i < 4; ++i)
#pragma unroll
    for (int j = 0; j < 4; ++j)
      atomicAdd(&ctx[((size_t)(b * NHEAD + h) * CHEAD + ty * 4 + i) * CHEAD + tx * 4 + j],
                cacc[i][j]);
}

// ---------------------------------------------------------------------------
// KD: M[b,o,h*64+d] = sum_e Wout[o,h*64+e] * ctx[b,h,d,e]. grid (4, 8, 8).
// ---------------------------------------------------------------------------
__global__ __launch_bounds__(256) void k_mmat(const float* __restrict__ Wout,
                                              const float* __restrict__ ctx,
                                              float* __restrict__ Mm) {
  __shared__ float Ws[64][65]; // [e][o]
  __shared__ float Csh[64][65]; // [e][d]
  const int tid = threadIdx.x;
  const int o0 = blockIdx.x * 64;
  const int h = blockIdx.y;
  const int b = blockIdx.z;

  for (int idx = tid; idx < 4096; idx += 256) {
    int r = idx >> 6, e = idx & 63;
    Ws[e][r] = Wout[(o0 + r) * HC + h * CHEAD + e];
    Csh[e][r] = ctx[((size_t)(b * NHEAD + h) * CHEAD + r) * CHEAD + e];
  }
  __syncthreads();
  const int tx = tid & 15, ty = tid >> 4;
  float acc[4][4];
#pragma unroll
  for (int i = 0; i < 4; ++i)
#pragma unroll
    for (int j = 0; j < 4; ++j) acc[i][j] = 0.f;
#pragma unroll 16
  for (int e = 0; e < 64; ++e) {
    float av[4], bv[4];
#pragma unroll
    for (int i = 0; i < 4; ++i) av[i] = Ws[e][ty * 4 + i];
#pragma unroll
    for (int j = 0; j < 4; ++j) bv[j] = Csh[e][tx * 4 + j];
#pragma unroll
    for (int i = 0; i < 4; ++i)
#pragma unroll
      for (int j = 0; j < 4; ++j) acc[i][j] = fmaf(av[i], bv[j], acc[i][j]);
  }
#pragma unroll
  for (int i = 0; i < 4; ++i)
#pragma unroll
    for (int j = 0; j < 4; ++j)
      Mm[(size_t)(b * D_DIM + o0 + ty * 4 + i) * HC + h * CHEAD + tx * 4 + j] = acc[i][j];
}

// ---------------------------------------------------------------------------
// KE: fused q-proj -> head-dim softmax -> y = M @ q_sm + bias; GN stats.
// grid (128 t-tiles of 64, 8 b), 256 thr. Thread owns rows {ty+16i}, cols tx*4+j.
// ---------------------------------------------------------------------------
__global__ __launch_bounds__(256) void k_fused_y(const float* __restrict__ Wq,
                                                 const float* __restrict__ x,
                                                 const float* __restrict__ Mm,
                                                 const float* __restrict__ bout,
                                                 float* __restrict__ out,
                                                 float* __restrict__ gnsum,
                                                 float* __restrict__ gnsumsq) {
  __shared__ float Wx[32][68];
  __shared__ float Xs[32][68];
  __shared__ float Qs[64][68];
  __shared__ float Msub[256][36];

  const int tid = threadIdx.x;
  const int tx = tid & 15, ty = tid >> 4;
  const int t0 = blockIdx.x * 64;
  const int b = blockIdx.y;

  float yacc[16][4];
#pragma unroll
  for (int i = 0; i < 16; ++i)
#pragma unroll
    for (int j = 0; j < 4; ++j) yacc[i][j] = 0.f;

  for (int h = 0; h < NHEAD; ++h) {
    // --- q GEMM: q_h[64 d][64 c]
    float qa[4][4];
#pragma unroll
    for (int i = 0; i < 4; ++i)
#pragma unroll
      for (int j = 0; j < 4; ++j) qa[i][j] = 0.f;
    for (int k0 = 0; k0 < D_DIM; k0 += 32) {
      __syncthreads();
      for (int idx = tid; idx < 32 * 64; idx += 256) {
        int kk = idx >> 6, r = idx & 63;
        Wx[kk][r] = Wq[(h * CHEAD + r) * D_DIM + k0 + kk];
        Xs[kk][r] = x[(b * D_DIM + k0 + kk) * T_DIM + t0 + r];
      }
      __syncthreads();
#pragma unroll
      for (int kk = 0; kk < 32; ++kk) {
        const float4 a4 = *reinterpret_cast<const float4*>(&Wx[kk][ty * 4]);
        const float4 c4 = *reinterpret_cast<const float4*>(&Xs[kk][tx * 4]);
        const float av[4] = {a4.x, a4.y, a4.z, a4.w};
        const float cv[4] = {c4.x, c4.y, c4.z, c4.w};
#pragma unroll
        for (int i = 0; i < 4; ++i)
#pragma unroll
          for (int j = 0; j < 4; ++j) qa[i][j] = fmaf(av[i], cv[j], qa[i][j]);
      }
    }
    __syncthreads();
#pragma unroll
    for (int i = 0; i < 4; ++i)
#pragma unroll
      for (int j = 0; j < 4; ++j) Qs[ty * 4 + i][tx * 4 + j] = qa[i][j];
    __syncthreads();
    // --- softmax over d (64 rows) per column, * QSCALE
    if (tid < 64) {
      const int c = tid;
      float m = -1e30f;
#pragma unroll 8
      for (int d = 0; d < 64; ++d) m = fmaxf(m, Qs[d][c]);
      float s = 0.f;
#pragma unroll 8
      for (int d = 0; d < 64; ++d) {
        const float e = __expf(Qs[d][c] - m);
        s += e;
        Qs[d][c] = e;
      }
      const float inv = QSCALE / s;
#pragma unroll 8
      for (int d = 0; d < 64; ++d) Qs[d][c] *= inv;
    }
    __syncthreads();
    // --- y += M[:, h*64+d] @ q_sm, two d-chunks of 32
    for (int dc = 0; dc < 2; ++dc) {
      for (int f4 = tid; f4 < 2048; f4 += 256) {
        const int r = f4 >> 3;
        const int dq = f4 & 7;
        const float4 v = *reinterpret_cast<const float4*>(
            &Mm[(size_t)(b * D_DIM + r) * HC + h * CHEAD + dc * 32 + dq * 4]);
        *reinterpret_cast<float4*>(&Msub[r][dq * 4]) = v;
      }
      __syncthreads();
#pragma unroll
      for (int d0 = 0; d0 < 32; d0 += 4) {
        const float4 q0 = *reinterpret_cast<const float4*>(&Qs[dc * 32 + d0 + 0][tx * 4]);
        const float4 q1 = *reinterpret_cast<const float4*>(&Qs[dc * 32 + d0 + 1][tx * 4]);
        const float4 q2 = *reinterpret_cast<const float4*>(&Qs[dc * 32 + d0 + 2][tx * 4]);
        const float4 q3 = *reinterpret_cast<const float4*>(&Qs[dc * 32 + d0 + 3][tx * 4]);
#pragma unroll
        for (int i = 0; i < 16; ++i) {
          const float4 m4 = *reinterpret_cast<const float4*>(&Msub[ty + 16 * i][d0]);
          yacc[i][0] = fmaf(m4.x, q0.x, fmaf(m4.y, q1.x, fmaf(m4.z, q2.x, fmaf(m4.w, q3.x, yacc[i][0]))));
          yacc[i][1] = fmaf(m4.x, q0.y, fmaf(m4.y, q1.y, fmaf(m4.z, q2.y, fmaf(m4.w, q3.y, yacc[i][1]))));
          yacc[i][2] = fmaf(m4.x, q0.z, fmaf(m4.y, q1.z, fmaf(m4.z, q2.z, fmaf(m4.w, q3.z, yacc[i][2]))));
          yacc[i][3] = fmaf(m4.x, q0.w, fmaf(m4.y, q1.w, fmaf(m4.z, q2.w, fmaf(m4.w, q3.w, yacc[i][3]))));
        }
      }
      __syncthreads();
    }
  }

  // --- epilogue: bias, store, GN stats (shfl reduce, 2 atomics/group/wave)
#pragma unroll
  for (int i = 0; i < 16; ++i) {
    const int row = ty + 16 * i;
    const float bias = bout[row];
    float s = 0.f, qq = 0.f;
#pragma unroll
    for (int j = 0; j < 4; ++j) {
      yacc[i][j] += bias;
      s += yacc[i][j];
      qq += yacc[i][j] * yacc[i][j];
    }
    *reinterpret_cast<float4*>(&out[(size_t)(b * D_DIM + row) * T_DIM + t0 + tx * 4]) =
        make_float4(yacc[i][0], yacc[i][1], yacc[i][2], yacc[i][3]);
    // reduce over tx (16 lanes), then over ty within wave (4 rows, same group)
#pragma unroll
    for (int off = 1; off <= 8; off <<= 1) {
      s += __shfl_xor(s, off);
      qq += __shfl_xor(qq, off);
    }
    s += __shfl_xor(s, 16); qq += __shfl_xor(qq, 16);
    s += __shfl_xor(s, 32); qq += __shfl_xor(qq, 32);
    if ((tid & 63) == 0) {
      const int g = 2 * i + (tid >> 7);
      atomicAdd(&gnsum[b * NGROUP + g], s);
      atomicAdd(&gnsumsq[b * NGROUP + g], qq);
    }
  }
}

// ---------------------------------------------------------------------------
// K7: finalize group stats. one block, 256 = 8b*32g.
// ---------------------------------------------------------------------------
__global__ void k_gnfin(const float* __restrict__ gnsum, const float* __restrict__ gnsumsq,
                        float* __restrict__ gnmean, float* __restrict__ gnrs) {
  const int tid = threadIdx.x;
  const float cnt = (float)((D_DIM / NGROUP) * T_DIM);
  float mean = gnsum[tid] / cnt;
  float var = gnsumsq[tid] / cnt - mean * mean;
  gnmean[tid] = mean;
  gnrs[tid] = rsqrtf(var + GN_EPS);
}

// ---------------------------------------------------------------------------
// K8: y = (y - mean)*rs*gamma + beta, in place on d_out, float4.
// ---------------------------------------------------------------------------
__global__ __launch_bounds__(256) void k_apply(float* __restrict__ out,
                                               const float* __restrict__ gnmean,
                                               const float* __restrict__ gnrs,
                                               const float* __restrict__ gamma,
                                               const float* __restrict__ beta) {
  const int n4 = (B_DIM * D_DIM * T_DIM) / 4;
  for (int i = blockIdx.x * 256 + threadIdx.x; i < n4; i += gridDim.x * 256) {
    float4 v = reinterpret_cast<const float4*>(out)[i];
    const int row = i >> 11;
    const int c = row & (D_DIM - 1);
    const int b = row >> 8;
    const int gi = b * NGROUP + (c >> 3);
    const float a = gnrs[gi] * gamma[c];
    const float bb = beta[c] - gnmean[gi] * a;
    v.x = v.x * a + bb; v.y = v.y * a + bb; v.z = v.z * a + bb; v.w = v.w * a + bb;
    reinterpret_cast<float4*>(out)[i] = v;
  }
}

// ---------------------------------------------------------------------------
extern "C" void kernel_launch(void* const* d_in, const int* in_sizes, int n_in,
                              void* d_out, int out_size, void* d_ws, size_t ws_size,
                              hipStream_t stream) {
  const float* x     = (const float*)d_in[0];
  const float* cs    = (const float*)d_in[1];
  const float* Wq    = (const float*)d_in[2];
  const float* Wkv   = (const float*)d_in[3];
  const float* Wout  = (const float*)d_in[4];
  const float* bout  = (const float*)d_in[5];
  const float* gamma = (const float*)d_in[6];
  const float* beta  = (const float*)d_in[7];
  float* out = (float*)d_out;
  char* ws = (char*)d_ws;

  float* chunkstats = (float*)(ws + CHUNK_OFF);
  float* kstats     = (float*)(ws + KST_OFF);
  float* ctx        = (float*)(ws + CTX_OFF);
  float* gnsum      = (float*)(ws + GNS_OFF);
  float* gnsumsq    = (float*)(ws + GNQ_OFF);
  float* gnmean     = (float*)(ws + GNM_OFF);
  float* gnrs       = (float*)(ws + GNR_OFF);
  float* Mm         = (float*)(ws + MM_OFF);

  k_zero   <<<(ZERO_FLOATS + 255) / 256, 256, 0, stream>>>(ctx, ZERO_FLOATS);
  k_kchunk <<<dim3(64, 4, 8), 256, 0, stream>>>(Wkv, cs, chunkstats);
  k_kcomb  <<<dim3(512, 8),   64,  0, stream>>>(chunkstats, kstats);
  k_ctx2   <<<dim3(8, 8, 8),  256, 0, stream>>>(Wkv, cs, kstats, ctx);
  k_mmat   <<<dim3(4, 8, 8),  256, 0, stream>>>(Wout, ctx, Mm);
  k_fused_y<<<dim3(128, 8),   256, 0, stream>>>(Wq, x, Mm, bout, out, gnsum, gnsumsq);
  k_gnfin  <<<1, 256, 0, stream>>>(gnsum, gnsumsq, gnmean, gnrs);
  k_apply  <<<4096, 256, 0, stream>>>(out, gnmean, gnrs, gamma, beta);
}

// Round 8
// 2025.669 us; speedup vs baseline: 1.3063x; 1.3063x over previous
//
#include <hip/hip_runtime.h>
#include <math.h>

// Problem constants
#define T_DIM 8192
#define B_DIM 8
#define D_DIM 256
#define CD_DIM 256
#define HC 512        // HEADS*DIM_HEAD
#define NHEAD 8
#define CHEAD 64
#define NGROUP 32
#define GN_EPS 1e-5f
#define QSCALE 0.125f

// ---------------------------------------------------------------------------
// Workspace layout (bytes) — total ~7.04 MB
//   0        chunkstats [b][512][64][2] f32   2,097,152
//   2097152  kstats     [b][512][2]           32,768
//   2129920  ctx        [b][8][64][64]        1,048,576   (zeroed)
//   3178496  gnsum      [b][32]               1,024       (zeroed)
//   3179520  gnsumsq    [b][32]               1,024       (zeroed)
//   3180544  gnmean     [b][32]               1,024
//   3181568  gnrs       [b][32]               1,024
//   3182592  Mm         [b][256][512]         4,194,304
// ---------------------------------------------------------------------------
#define CHUNK_OFF   0ull
#define KST_OFF     2097152ull
#define CTX_OFF     2129920ull
#define GNS_OFF     3178496ull
#define GNQ_OFF     3179520ull
#define GNM_OFF     3180544ull
#define GNR_OFF     3181568ull
#define MM_OFF      3182592ull
#define ZERO_FLOATS 262656   // ctx + gnsum + gnsumsq

__global__ __launch_bounds__(256) void k_zero(float* __restrict__ p, int n) {
  int i = blockIdx.x * 256 + threadIdx.x;
  if (i < n) p[i] = 0.f;
}

// ---------------------------------------------------------------------------
// KA: k = Wkv[0:512] @ cs, per (row, 128-col chunk) max & sumexp -> chunkstats.
// UNCHANGED (staging already coalesced; k-order must stay bitwise identical
// to KC).
// ---------------------------------------------------------------------------
__global__ __launch_bounds__(256) void k_kchunk(const float* __restrict__ Wkv,
                                                const float* __restrict__ cs,
                                                float* __restrict__ chunkstats) {
  __shared__ float As[32][132];
  __shared__ float Bs[32][132];
  __shared__ float Rm[128][17];
  __shared__ float Rs[128][17];
  __shared__ float Ms[128];

  const int tid = threadIdx.x;
  const int tx = tid & 15, ty = tid >> 4;
  const int chunk = blockIdx.x;
  const int t0 = chunk * 128;
  const int rb = blockIdx.y * 128;
  const int b = blockIdx.z;

  float acc[8][8];
#pragma unroll
  for (int i = 0; i < 8; ++i)
#pragma unroll
    for (int j = 0; j < 8; ++j) acc[i][j] = 0.f;

  for (int k0 = 0; k0 < CD_DIM; k0 += 32) {
    for (int idx = tid; idx < 128 * 32; idx += 256) {
      int r = idx >> 5, kk = idx & 31;
      As[kk][r] = Wkv[(rb + r) * CD_DIM + k0 + kk];
    }
    for (int idx = tid; idx < 32 * 128; idx += 256) {
      int kk = idx >> 7, c = idx & 127;
      Bs[kk][c] = cs[(b * CD_DIM + k0 + kk) * T_DIM + t0 + c];
    }
    __syncthreads();
#pragma unroll
    for (int kk = 0; kk < 32; ++kk) {
      const float4 a0 = *reinterpret_cast<const float4*>(&As[kk][ty * 8]);
      const float4 a1 = *reinterpret_cast<const float4*>(&As[kk][ty * 8 + 4]);
      const float4 b0 = *reinterpret_cast<const float4*>(&Bs[kk][tx * 8]);
      const float4 b1 = *reinterpret_cast<const float4*>(&Bs[kk][tx * 8 + 4]);
      const float av[8] = {a0.x, a0.y, a0.z, a0.w, a1.x, a1.y, a1.z, a1.w};
      const float bv[8] = {b0.x, b0.y, b0.z, b0.w, b1.x, b1.y, b1.z, b1.w};
#pragma unroll
      for (int i = 0; i < 8; ++i)
#pragma unroll
        for (int j = 0; j < 8; ++j) acc[i][j] = fmaf(av[i], bv[j], acc[i][j]);
    }
    __syncthreads();
  }

#pragma unroll
  for (int i = 0; i < 8; ++i) {
    float pm = acc[i][0];
#pragma unroll
    for (int j = 1; j < 8; ++j) pm = fmaxf(pm, acc[i][j]);
    Rm[ty * 8 + i][tx] = pm;
  }
  __syncthreads();
  if (tid < 128) {
    float m = Rm[tid][0];
#pragma unroll
    for (int jj = 1; jj < 16; ++jj) m = fmaxf(m, Rm[tid][jj]);
    Ms[tid] = m;
  }
  __syncthreads();
#pragma unroll
  for (int i = 0; i < 8; ++i) {
    const float m = Ms[ty * 8 + i];
    float ps = 0.f;
#pragma unroll
    for (int j = 0; j < 8; ++j) ps += __expf(acc[i][j] - m);
    Rs[ty * 8 + i][tx] = ps;
  }
  __syncthreads();
  if (tid < 128) {
    float s = 0.f;
#pragma unroll
    for (int jj = 0; jj < 16; ++jj) s += Rs[tid][jj];
    const size_t o = ((size_t)(b * HC + rb + tid) * 64 + chunk) * 2;
    chunkstats[o] = Ms[tid];
    chunkstats[o + 1] = s;
  }
}

// ---------------------------------------------------------------------------
// KB: combine 64 chunk stats per row -> (m, 1/Z). grid (512, 8), 64 threads.
// ---------------------------------------------------------------------------
__global__ __launch_bounds__(64) void k_kcomb(const float* __restrict__ chunkstats,
                                              float* __restrict__ kstats) {
  const int r = blockIdx.x;
  const int b = blockIdx.y;
  const int lane = threadIdx.x;
  const size_t o = ((size_t)(b * HC + r) * 64 + lane) * 2;
  float m = chunkstats[o];
  float s = chunkstats[o + 1];
#pragma unroll
  for (int off = 32; off > 0; off >>= 1) {
    float m2 = __shfl_xor(m, off);
    float s2 = __shfl_xor(s, off);
    float mn = fmaxf(m, m2);
    s = s * __expf(m - mn) + s2 * __expf(m2 - mn);
    m = mn;
  }
  if (lane == 0) {
    kstats[(b * HC + r) * 2] = m;
    kstats[(b * HC + r) * 2 + 1] = 1.f / s;
  }
}

// ---------------------------------------------------------------------------
// KC: recompute k (bitwise same order as KA) and v per 64x64 subtile;
// ctx[d][e] += sum_t exp(k[d,t]-m[d])/Z[d] * v[e,t]. grid (8 tc, 8 h, 8 b).
// Wk/Wv staging lane-remap to kk-fast (coalesced global); staged VALUES
// identical -> k stays bitwise consistent with KA.
// ---------------------------------------------------------------------------
__global__ __launch_bounds__(256) void k_ctx2(const float* __restrict__ Wkv,
                                              const float* __restrict__ cs,
                                              const float* __restrict__ kstats,
                                              float* __restrict__ ctx) {
  __shared__ float Wk[32][68];
  __shared__ float Wv[32][68];
  __shared__ float Cs[32][68];
  __shared__ float Ks[64][68];  // [tt][d]
  __shared__ float Vs[64][68];  // [tt][e]

  const int tid = threadIdx.x;
  const int tx = tid & 15, ty = tid >> 4;
  const int tc0 = blockIdx.x * 1024;
  const int h = blockIdx.y;
  const int b = blockIdx.z;

  float msr[4], zsr[4];
#pragma unroll
  for (int i = 0; i < 4; ++i) {
    msr[i] = kstats[(b * HC + h * CHEAD + ty * 4 + i) * 2];
    zsr[i] = kstats[(b * HC + h * CHEAD + ty * 4 + i) * 2 + 1];
  }

  float cacc[4][4];
#pragma unroll
  for (int i = 0; i < 4; ++i)
#pragma unroll
    for (int j = 0; j < 4; ++j) cacc[i][j] = 0.f;

  for (int sc = 0; sc < 16; ++sc) {
    const int t0 = tc0 + sc * 64;
    float ka[4][4], va[4][4];
#pragma unroll
    for (int i = 0; i < 4; ++i)
#pragma unroll
      for (int j = 0; j < 4; ++j) { ka[i][j] = 0.f; va[i][j] = 0.f; }

    for (int k0 = 0; k0 < CD_DIM; k0 += 32) {
      __syncthreads();
      for (int idx = tid; idx < 32 * 64; idx += 256) {
        // weights: kk fastest -> coalesced 128B global segments
        int kk = idx & 31, r = idx >> 5;
        Wk[kk][r] = Wkv[(h * CHEAD + r) * CD_DIM + k0 + kk];
        Wv[kk][r] = Wkv[(HC + h * CHEAD + r) * CD_DIM + k0 + kk];
        // activations: col fastest -> already coalesced
        int kk2 = idx >> 6, r2 = idx & 63;
        Cs[kk2][r2] = cs[(b * CD_DIM + k0 + kk2) * T_DIM + t0 + r2];
      }
      __syncthreads();
#pragma unroll
      for (int kk = 0; kk < 32; ++kk) {
        const float4 a4 = *reinterpret_cast<const float4*>(&Wk[kk][ty * 4]);
        const float4 w4 = *reinterpret_cast<const float4*>(&Wv[kk][ty * 4]);
        const float4 c4 = *reinterpret_cast<const float4*>(&Cs[kk][tx * 4]);
        const float av[4] = {a4.x, a4.y, a4.z, a4.w};
        const float wv[4] = {w4.x, w4.y, w4.z, w4.w};
        const float cv[4] = {c4.x, c4.y, c4.z, c4.w};
#pragma unroll
        for (int i = 0; i < 4; ++i)
#pragma unroll
          for (int j = 0; j < 4; ++j) {
            ka[i][j] = fmaf(av[i], cv[j], ka[i][j]);
            va[i][j] = fmaf(wv[i], cv[j], va[i][j]);
          }
      }
    }
    __syncthreads();
#pragma unroll
    for (int i = 0; i < 4; ++i)
#pragma unroll
      for (int j = 0; j < 4; ++j) {
        Ks[tx * 4 + j][ty * 4 + i] = __expf(ka[i][j] - msr[i]) * zsr[i];
        Vs[tx * 4 + j][ty * 4 + i] = va[i][j];
      }
    __syncthreads();
#pragma unroll 8
    for (int tt = 0; tt < 64; ++tt) {
      const float4 kd = *reinterpret_cast<const float4*>(&Ks[tt][ty * 4]);
      const float4 ve = *reinterpret_cast<const float4*>(&Vs[tt][tx * 4]);
      const float kv_[4] = {kd.x, kd.y, kd.z, kd.w};
      const float vv[4] = {ve.x, ve.y, ve.z, ve.w};
#pragma unroll
      for (int i = 0; i < 4; ++i)
#pragma unroll
        for (int j = 0; j < 4; ++j) cacc[i][j] = fmaf(kv_[i], vv[j], cacc[i][j]);
    }
  }
#pragma unroll
  for (int i = 0; i < 4; ++i)
#pragma unroll
    for (int j = 0; j < 4; ++j)
      atomicAdd(&ctx[((size_t)(b * NHEAD + h) * CHEAD + ty * 4 + i) * CHEAD + tx * 4 + j],
                cacc[i][j]);
}

// ---------------------------------------------------------------------------
// KD: M[b,o,h*64+d] = sum_e Wout[o,h*64+e] * ctx[b,h,d,e]. grid (4, 8, 8).
// ---------------------------------------------------------------------------
__global__ __launch_bounds__(256) void k_mmat(const float* __restrict__ Wout,
                                              const float* __restrict__ ctx,
                                              float* __restrict__ Mm) {
  __shared__ float Ws[64][65]; // [e][o]
  __shared__ float Csh[64][65]; // [e][d]
  const int tid = threadIdx.x;
  const int o0 = blockIdx.x * 64;
  const int h = blockIdx.y;
  const int b = blockIdx.z;

  for (int idx = tid; idx < 4096; idx += 256) {
    int r = idx >> 6, e = idx & 63;
    Ws[e][r] = Wout[(o0 + r) * HC + h * CHEAD + e];
    Csh[e][r] = ctx[((size_t)(b * NHEAD + h) * CHEAD + r) * CHEAD + e];
  }
  __syncthreads();
  const int tx = tid & 15, ty = tid >> 4;
  float acc[4][4];
#pragma unroll
  for (int i = 0; i < 4; ++i)
#pragma unroll
    for (int j = 0; j < 4; ++j) acc[i][j] = 0.f;
#pragma unroll 16
  for (int e = 0; e < 64; ++e) {
    float av[4], bv[4];
#pragma unroll
    for (int i = 0; i < 4; ++i) av[i] = Ws[e][ty * 4 + i];
#pragma unroll
    for (int j = 0; j < 4; ++j) bv[j] = Csh[e][tx * 4 + j];
#pragma unroll
    for (int i = 0; i < 4; ++i)
#pragma unroll
      for (int j = 0; j < 4; ++j) acc[i][j] = fmaf(av[i], bv[j], acc[i][j]);
  }
#pragma unroll
  for (int i = 0; i < 4; ++i)
#pragma unroll
    for (int j = 0; j < 4; ++j)
      Mm[(size_t)(b * D_DIM + o0 + ty * 4 + i) * HC + h * CHEAD + tx * 4 + j] = acc[i][j];
}

// ---------------------------------------------------------------------------
// KE v2: fused q-proj -> head-dim softmax -> y = M @ q_sm + bias; GN stats.
// (counters r6: 1472us, VALU 21%, Occ 11.9% -> latency-bound):
//  * coalesced Wq staging (kk-fast lanes; was stride-256 uncoalesced)
//  * KC=64 chunks + register-prefetch pipeline (global latency hidden by FMA)
//  * Mm read direct from global (L2-resident, 16-lane broadcast) — no Msub LDS
//  * LDS 52224B -> 3 blocks/CU (was 71680 -> 2)
//  * wave-parallel softmax (all 256 threads; was 64)
// q/PV fmaf accumulation order preserved bitwise vs round 6.
// ---------------------------------------------------------------------------
__global__ __launch_bounds__(256, 3) void k_fused_y(const float* __restrict__ Wq,
                                                    const float* __restrict__ x,
                                                    const float* __restrict__ Mm,
                                                    const float* __restrict__ bout,
                                                    float* __restrict__ out,
                                                    float* __restrict__ gnsum,
                                                    float* __restrict__ gnsumsq) {
  __shared__ float Wx[64][68];   // [kk][d-row]   17408 B
  __shared__ float Xs[64][68];   // [kk][t-col]   17408 B (also softmax scratch)
  __shared__ float Qs[64][68];   // [d][t-col]    17408 B

  const int tid = threadIdx.x;
  const int tx = tid & 15, ty = tid >> 4;
  const int t0 = blockIdx.x * 64;
  const int b = blockIdx.y;

  // staging lane roles (fixed per thread)
  const int wkk = tid & 63;       // Wq: kk fastest -> coalesced
  const int wr0 = tid >> 6;       // Wq: base row, +4 per step
  const int xcq = tid & 15;       // x: col-quad fastest -> coalesced float4
  const int xk0 = tid >> 4;       // x: base kk, +16 per step

  float yacc[16][4];
#pragma unroll
  for (int i = 0; i < 16; ++i)
#pragma unroll
    for (int j = 0; j < 4; ++j) yacc[i][j] = 0.f;

  float wq[16];
  float4 xv[4];

  for (int h = 0; h < NHEAD; ++h) {
    float qa[4][4];
#pragma unroll
    for (int i = 0; i < 4; ++i)
#pragma unroll
      for (int j = 0; j < 4; ++j) qa[i][j] = 0.f;

    // prefetch chunk 0
    {
      const float* wp = Wq + (size_t)(h * CHEAD + wr0) * D_DIM + wkk;
#pragma unroll
      for (int t = 0; t < 16; ++t) wq[t] = wp[(size_t)t * 4 * D_DIM];
      const float* xp = x + ((size_t)b * D_DIM + xk0) * T_DIM + t0 + xcq * 4;
#pragma unroll
      for (int t = 0; t < 4; ++t)
        xv[t] = *reinterpret_cast<const float4*>(xp + (size_t)t * 16 * T_DIM);
    }

    for (int kc = 0; kc < 4; ++kc) {
      // write prefetched regs -> LDS
#pragma unroll
      for (int t = 0; t < 16; ++t) Wx[wkk][wr0 + 4 * t] = wq[t];
#pragma unroll
      for (int t = 0; t < 4; ++t)
        *reinterpret_cast<float4*>(&Xs[xk0 + 16 * t][xcq * 4]) = xv[t];
      __syncthreads();

      // issue next chunk's loads (latency overlaps FMA below)
      if (kc < 3) {
        const int k0 = (kc + 1) * 64;
        const float* wp = Wq + (size_t)(h * CHEAD + wr0) * D_DIM + k0 + wkk;
#pragma unroll
        for (int t = 0; t < 16; ++t) wq[t] = wp[(size_t)t * 4 * D_DIM];
        const float* xp = x + ((size_t)b * D_DIM + k0 + xk0) * T_DIM + t0 + xcq * 4;
#pragma unroll
        for (int t = 0; t < 4; ++t)
          xv[t] = *reinterpret_cast<const float4*>(xp + (size_t)t * 16 * T_DIM);
      }

#pragma unroll 16
      for (int kk = 0; kk < 64; ++kk) {
        const float4 a4 = *reinterpret_cast<const float4*>(&Wx[kk][ty * 4]);
        const float4 c4 = *reinterpret_cast<const float4*>(&Xs[kk][tx * 4]);
        const float av[4] = {a4.x, a4.y, a4.z, a4.w};
        const float cv[4] = {c4.x, c4.y, c4.z, c4.w};
#pragma unroll
        for (int i = 0; i < 4; ++i)
#pragma unroll
          for (int j = 0; j < 4; ++j) qa[i][j] = fmaf(av[i], cv[j], qa[i][j]);
      }
      __syncthreads();
    }

    // qa -> Qs (float4 rows)
#pragma unroll
    for (int i = 0; i < 4; ++i)
      *reinterpret_cast<float4*>(&Qs[ty * 4 + i][tx * 4]) =
          make_float4(qa[i][0], qa[i][1], qa[i][2], qa[i][3]);
    __syncthreads();

    // softmax over d (64 rows) per column; thread (qt,c) owns rows qt*16..+15
    {
      const int c = tid & 63;
      const int qt = tid >> 6;
      float pm = -1e30f;
#pragma unroll
      for (int r = 0; r < 16; ++r) pm = fmaxf(pm, Qs[qt * 16 + r][c]);
      Xs[qt][c] = pm;
      __syncthreads();
      const float m = fmaxf(fmaxf(Xs[0][c], Xs[1][c]), fmaxf(Xs[2][c], Xs[3][c]));
      float ps = 0.f;
#pragma unroll
      for (int r = 0; r < 16; ++r) {
        const float e = __expf(Qs[qt * 16 + r][c] - m);
        Qs[qt * 16 + r][c] = e;
        ps += e;
      }
      Xs[8 + qt][c] = ps;
      __syncthreads();
      const float s4 = Xs[8][c] + Xs[9][c] + Xs[10][c] + Xs[11][c];
      const float inv = QSCALE / s4;
#pragma unroll
      for (int r = 0; r < 16; ++r) Qs[qt * 16 + r][c] *= inv;
      __syncthreads();
    }

    // PV: yacc[o][c] += sum_d Mm[b][o][h*64+d] * Qs[d][c]; Mm via global
    // broadcast (16 lanes share each address; L2-resident).
    {
      const float* Mb = Mm + (size_t)b * D_DIM * HC + h * CHEAD;
#pragma unroll 4
      for (int d0 = 0; d0 < 64; d0 += 4) {
        const float4 q0 = *reinterpret_cast<const float4*>(&Qs[d0 + 0][tx * 4]);
        const float4 q1 = *reinterpret_cast<const float4*>(&Qs[d0 + 1][tx * 4]);
        const float4 q2 = *reinterpret_cast<const float4*>(&Qs[d0 + 2][tx * 4]);
        const float4 q3 = *reinterpret_cast<const float4*>(&Qs[d0 + 3][tx * 4]);
#pragma unroll
        for (int i = 0; i < 16; ++i) {
          const float4 m4 =
              *reinterpret_cast<const float4*>(Mb + (size_t)(ty + 16 * i) * HC + d0);
          yacc[i][0] = fmaf(m4.x, q0.x, fmaf(m4.y, q1.x, fmaf(m4.z, q2.x, fmaf(m4.w, q3.x, yacc[i][0]))));
          yacc[i][1] = fmaf(m4.x, q0.y, fmaf(m4.y, q1.y, fmaf(m4.z, q2.y, fmaf(m4.w, q3.y, yacc[i][1]))));
          yacc[i][2] = fmaf(m4.x, q0.z, fmaf(m4.y, q1.z, fmaf(m4.z, q2.z, fmaf(m4.w, q3.z, yacc[i][2]))));
          yacc[i][3] = fmaf(m4.x, q0.w, fmaf(m4.y, q1.w, fmaf(m4.z, q2.w, fmaf(m4.w, q3.w, yacc[i][3]))));
        }
      }
    }
    // no barrier needed: next write to Qs is separated by the q-GEMM barriers
  }

  // epilogue: bias, store, GN stats (identical to round 6)
#pragma unroll
  for (int i = 0; i < 16; ++i) {
    const int row = ty + 16 * i;
    const float bias = bout[row];
    float s = 0.f, qq = 0.f;
#pragma unroll
    for (int j = 0; j < 4; ++j) {
      yacc[i][j] += bias;
      s += yacc[i][j];
      qq += yacc[i][j] * yacc[i][j];
    }
    *reinterpret_cast<float4*>(&out[(size_t)(b * D_DIM + row) * T_DIM + t0 + tx * 4]) =
        make_float4(yacc[i][0], yacc[i][1], yacc[i][2], yacc[i][3]);
#pragma unroll
    for (int off = 1; off <= 8; off <<= 1) {
      s += __shfl_xor(s, off);
      qq += __shfl_xor(qq, off);
    }
    s += __shfl_xor(s, 16); qq += __shfl_xor(qq, 16);
    s += __shfl_xor(s, 32); qq += __shfl_xor(qq, 32);
    if ((tid & 63) == 0) {
      const int g = 2 * i + (tid >> 7);
      atomicAdd(&gnsum[b * NGROUP + g], s);
      atomicAdd(&gnsumsq[b * NGROUP + g], qq);
    }
  }
}

// ---------------------------------------------------------------------------
// K7: finalize group stats. one block, 256 = 8b*32g.
// ---------------------------------------------------------------------------
__global__ void k_gnfin(const float* __restrict__ gnsum, const float* __restrict__ gnsumsq,
                        float* __restrict__ gnmean, float* __restrict__ gnrs) {
  const int tid = threadIdx.x;
  const float cnt = (float)((D_DIM / NGROUP) * T_DIM);
  float mean = gnsum[tid] / cnt;
  float var = gnsumsq[tid] / cnt - mean * mean;
  gnmean[tid] = mean;
  gnrs[tid] = rsqrtf(var + GN_EPS);
}

// ---------------------------------------------------------------------------
// K8: y = (y - mean)*rs*gamma + beta, in place on d_out, float4.
// ---------------------------------------------------------------------------
__global__ __launch_bounds__(256) void k_apply(float* __restrict__ out,
                                               const float* __restrict__ gnmean,
                                               const float* __restrict__ gnrs,
                                               const float* __restrict__ gamma,
                                               const float* __restrict__ beta) {
  const int n4 = (B_DIM * D_DIM * T_DIM) / 4;
  for (int i = blockIdx.x * 256 + threadIdx.x; i < n4; i += gridDim.x * 256) {
    float4 v = reinterpret_cast<const float4*>(out)[i];
    const int row = i >> 11;
    const int c = row & (D_DIM - 1);
    const int b = row >> 8;
    const int gi = b * NGROUP + (c >> 3);
    const float a = gnrs[gi] * gamma[c];
    const float bb = beta[c] - gnmean[gi] * a;
    v.x = v.x * a + bb; v.y = v.y * a + bb; v.z = v.z * a + bb; v.w = v.w * a + bb;
    reinterpret_cast<float4*>(out)[i] = v;
  }
}

// ---------------------------------------------------------------------------
extern "C" void kernel_launch(void* const* d_in, const int* in_sizes, int n_in,
                              void* d_out, int out_size, void* d_ws, size_t ws_size,
                              hipStream_t stream) {
  const float* x     = (const float*)d_in[0];
  const float* cs    = (const float*)d_in[1];
  const float* Wq    = (const float*)d_in[2];
  const float* Wkv   = (const float*)d_in[3];
  const float* Wout  = (const float*)d_in[4];
  const float* bout  = (const float*)d_in[5];
  const float* gamma = (const float*)d_in[6];
  const float* beta  = (const float*)d_in[7];
  float* out = (float*)d_out;
  char* ws = (char*)d_ws;

  float* chunkstats = (float*)(ws + CHUNK_OFF);
  float* kstats     = (float*)(ws + KST_OFF);
  float* ctx        = (float*)(ws + CTX_OFF);
  float* gnsum      = (float*)(ws + GNS_OFF);
  float* gnsumsq    = (float*)(ws + GNQ_OFF);
  float* gnmean     = (float*)(ws + GNM_OFF);
  float* gnrs       = (float*)(ws + GNR_OFF);
  float* Mm         = (float*)(ws + MM_OFF);

  k_zero   <<<(ZERO_FLOATS + 255) / 256, 256, 0, stream>>>(ctx, ZERO_FLOATS);
  k_kchunk <<<dim3(64, 4, 8), 256, 0, stream>>>(Wkv, cs, chunkstats);
  k_kcomb  <<<dim3(512, 8),   64,  0, stream>>>(chunkstats, kstats);
  k_ctx2   <<<dim3(8, 8, 8),  256, 0, stream>>>(Wkv, cs, kstats, ctx);
  k_mmat   <<<dim3(4, 8, 8),  256, 0, stream>>>(Wout, ctx, Mm);
  k_fused_y<<<dim3(128, 8),   256, 0, stream>>>(Wq, x, Mm, bout, out, gnsum, gnsumsq);
  k_gnfin  <<<1, 256, 0, stream>>>(gnsum, gnsumsq, gnmean, gnrs);
  k_apply  <<<4096, 256, 0, stream>>>(out, gnmean, gnrs, gamma, beta);
}